// Round 2
// baseline (2406.532 us; speedup 1.0000x reference)
//
#include <hip/hip_runtime.h>
#include <stdint.h>

typedef unsigned short u16;
typedef uint32_t u32;
typedef __attribute__((ext_vector_type(8))) short short8;
typedef __attribute__((ext_vector_type(4))) float f32x4;

__device__ __forceinline__ float bf2f(u16 v) {
  union { u32 u; float f; } c; c.u = ((u32)v) << 16; return c.f;
}
__device__ __forceinline__ u16 f2bf(float f) {
  union { float f; u32 u; } c; c.f = f;
  u32 r = c.u + 0x7fffu + ((c.u >> 16) & 1u);  // RNE
  return (u16)(r >> 16);
}
__device__ __forceinline__ void mode_store(void* p, size_t idx, float v, u32 fm) {
  if (fm) ((float*)p)[idx] = v;
  else    ((u16*)p)[idx]   = f2bf(v);
}

enum { EPI_PLANES = 0, EPI_EMB = 1, EPI_SCORES = 2, EPI_OUT = 3 };

// ---- dtype detection: low u16 of fp32 data is random mantissa bits -> wild bf16 ----
__global__ void detect_kernel(const u32* __restrict__ x, u32* __restrict__ flag) {
  __shared__ int cnt;
  if (threadIdx.x == 0) cnt = 0;
  __syncthreads();
  int wild = 0;
  #pragma unroll
  for (int c = 0; c < 4; ++c) {
    u32 u = x[threadIdx.x * 4 + c];
    float a = fabsf(bf2f((u16)(u & 0xffff)));
    if (!(a <= 1e6f) || (a != 0.f && a < 1e-20f)) wild++;  // !(a<=..) catches NaN
  }
  atomicAdd(&cnt, wild);
  __syncthreads();
  if (threadIdx.x == 0) flag[0] = (cnt > 100) ? 1u : 0u;  // 1 = fp32 inputs
}

// ---- canonicalize any input array to f32 (biases, centers) ----
__global__ void convert_kernel(const void* __restrict__ in, float* __restrict__ out,
                               int n, const u32* __restrict__ flag) {
  int i = blockIdx.x * 256 + threadIdx.x;
  if (i >= n) return;
  u32 fm = flag[0];
  out[i] = fm ? ((const float*)in)[i] : bf2f(((const u16*)in)[i]);
}

// ---- W[R=K][C=N] raw -> WT[N][K] in 3 bf16 planes (hi/mid/lo) ----
__global__ void trans_decomp_kernel(const void* __restrict__ in,
                                    u16* __restrict__ hi, u16* __restrict__ mid,
                                    u16* __restrict__ lo, int R, int C,
                                    const u32* __restrict__ flag) {
  __shared__ float t[32][33];
  u32 fm = flag[0];
  int x  = threadIdx.x & 31;
  int yq = threadIdx.x >> 5;
  int bx = blockIdx.x, by = blockIdx.y;
  #pragma unroll
  for (int yy = yq; yy < 32; yy += 8) {
    size_t src = (size_t)(by * 32 + yy) * C + bx * 32 + x;
    t[yy][x] = fm ? ((const float*)in)[src] : bf2f(((const u16*)in)[src]);
  }
  __syncthreads();
  #pragma unroll
  for (int yy = yq; yy < 32; yy += 8) {
    float v = t[x][yy];
    u16 h = f2bf(v);
    float r1 = v - bf2f(h);
    u16 m = f2bf(r1);
    u16 l = f2bf(r1 - bf2f(m));
    size_t dst = (size_t)(bx * 32 + yy) * R + by * 32 + x;
    hi[dst] = h; mid[dst] = m; lo[dst] = l;
  }
}

// ---- centers f32 -> 3 bf16 planes (same [K][D] layout, already B^T form) ----
__global__ void decomp_kernel(const float* __restrict__ in, u16* __restrict__ hi,
                              u16* __restrict__ mid, u16* __restrict__ lo, int n) {
  int i = blockIdx.x * 256 + threadIdx.x;
  if (i >= n) return;
  float v = in[i];
  u16 h = f2bf(v);
  float r1 = v - bf2f(h);
  u16 m = f2bf(r1);
  hi[i] = h; mid[i] = m; lo[i] = f2bf(r1 - bf2f(m));
}

// ---- c2[k] = sum_d centers[k][d]^2, from f32 centers, D=256 K=1024 ----
__global__ void c2_kernel(const float* __restrict__ cf, float* __restrict__ c2) {
  int w    = blockIdx.x * 4 + (threadIdx.x >> 6);
  int lane = threadIdx.x & 63;
  float4 v = *(const float4*)&cf[(size_t)w * 256 + lane * 4];
  float s = v.x * v.x + v.y * v.y + v.z * v.z + v.w * v.w;
  #pragma unroll
  for (int off = 32; off; off >>= 1) s += __shfl_down(s, off);
  if (lane == 0) c2[w] = s;
}

// ---- x chunk -> 3 bf16 planes (with element offset; dtype handled device-side) ----
__global__ void decomp_x_kernel(const void* __restrict__ in, u16* __restrict__ hi,
                                u16* __restrict__ mid, u16* __restrict__ lo,
                                int n, size_t eoff, const u32* __restrict__ flag) {
  int i = blockIdx.x * 256 + threadIdx.x;
  if (i >= n) return;
  u32 fm = flag[0];
  float v = fm ? ((const float*)in)[eoff + i] : bf2f(((const u16*)in)[eoff + i]);
  u16 h = f2bf(v);
  float r1 = v - bf2f(h);
  u16 m = f2bf(r1);
  hi[i] = h; mid[i] = m; lo[i] = f2bf(r1 - bf2f(m));
}

// ======================= 128x128 4-wave kernel (small layers) =======================

__device__ __forceinline__ void stage_tile128(const u16* __restrict__ g, u16* lbase,
                                              int Kst, int tid) {
  const int lane = tid & 63;
  const int wv   = tid >> 6;
  #pragma unroll
  for (int c = 0; c < 2; ++c) {
    const int li   = wv * 128 + c * 64 + lane;   // 16B-chunk index, 0..511
    const int row  = li >> 2;
    const int colb = (li & 3) * 16;
    const char* src = (const char*)g + (size_t)row * ((size_t)Kst * 2) + colb;
    u16* dst = lbase + (size_t)(wv * 128 + c * 64) * 8;  // wave-uniform
    __builtin_amdgcn_global_load_lds(
        (const __attribute__((address_space(1))) void*)src,
        (__attribute__((address_space(3))) void*)dst, 16, 0, 0);
  }
}

template<int nA, int nW, int PCAP, int RELU, int EPI, int NOUT>
__device__ __forceinline__ void gemm_body(
    const u16* __restrict__ A0, const u16* __restrict__ A1, const u16* __restrict__ A2,
    const u16* __restrict__ W0, const u16* __restrict__ W1, const u16* __restrict__ W2,
    const float* __restrict__ bias, const float* __restrict__ c2p,
    u16* __restrict__ O0, u16* __restrict__ O1, u16* __restrict__ O2,
    float* __restrict__ outf, void* __restrict__ dout, size_t doff,
    u32 fm, int M, int N, int K, u16* lds)
{
  const int tid  = threadIdx.x;
  const int lane = tid & 63;
  const int wid  = tid >> 6;
  const int m0 = blockIdx.y * 128;
  const int n0 = blockIdx.x * 128;
  const int wm = (wid & 1) * 64;
  const int wn = (wid >> 1) * 64;
  const u16* Ap[3] = {A0, A1, A2};
  const u16* Wp[3] = {W0, W1, W2};

  f32x4 acc[4][4];
  #pragma unroll
  for (int i = 0; i < 4; ++i)
    #pragma unroll
    for (int j = 0; j < 4; ++j)
      acc[i][j] = f32x4{0.f, 0.f, 0.f, 0.f};

  for (int k0 = 0; k0 < K; k0 += 32) {
    __syncthreads();
    #pragma unroll
    for (int p = 0; p < nA; ++p)
      stage_tile128(Ap[p] + (size_t)m0 * K + k0, lds + p * 4096, K, tid);
    #pragma unroll
    for (int q = 0; q < nW; ++q)
      stage_tile128(Wp[q] + (size_t)n0 * K + k0, lds + (nA + q) * 4096, K, tid);
    __syncthreads();

    short8 bfrag[nW][4];
    #pragma unroll
    for (int q = 0; q < nW; ++q)
      #pragma unroll
      for (int j = 0; j < 4; ++j) {
        int r = wn + j * 16 + (lane & 15);
        bfrag[q][j] = *(const short8*)&lds[(nA + q) * 4096 + r * 32 + (lane >> 4) * 8];
      }
    #pragma unroll
    for (int pa = 0; pa < nA; ++pa) {
      short8 afrag[4];
      #pragma unroll
      for (int i = 0; i < 4; ++i) {
        int r = wm + i * 16 + (lane & 15);
        afrag[i] = *(const short8*)&lds[pa * 4096 + r * 32 + (lane >> 4) * 8];
      }
      #pragma unroll
      for (int pw = 0; pw < nW; ++pw) {
        if (pa + pw <= PCAP) {
          #pragma unroll
          for (int i = 0; i < 4; ++i)
            #pragma unroll
            for (int j = 0; j < 4; ++j)
              acc[i][j] = __builtin_amdgcn_mfma_f32_16x16x32_bf16(
                  afrag[i], bfrag[pw][j], acc[i][j], 0, 0, 0);
        }
      }
    }
  }

  #pragma unroll
  for (int i = 0; i < 4; ++i) {
    int rbase = m0 + wm + i * 16 + ((lane >> 4) * 4);
    #pragma unroll
    for (int j = 0; j < 4; ++j) {
      int col = n0 + wn + j * 16 + (lane & 15);
      float bv = 0.f, c2v = 0.f;
      if (EPI != EPI_SCORES) bv = bias[col];
      if (EPI == EPI_SCORES) c2v = c2p[col];
      #pragma unroll
      for (int r = 0; r < 4; ++r) {
        float v = acc[i][j][r] + bv;
        if (RELU) v = fmaxf(v, 0.f);
        size_t idx = (size_t)(rbase + r) * N + col;
        if (EPI == EPI_SCORES) {
          outf[idx] = c2v - 2.f * v;
        } else {
          if (NOUT >= 1) {
            u16 h = f2bf(v);
            O0[idx] = h;
            if (NOUT >= 2) {
              float r1 = v - bf2f(h);
              u16 m = f2bf(r1);
              O1[idx] = m;
              if (NOUT >= 3) O2[idx] = f2bf(r1 - bf2f(m));
            }
          }
          if (EPI == EPI_EMB || EPI == EPI_OUT) mode_store(dout, doff + idx, v, fm);
        }
      }
    }
  }
}

template<int NA, int NW, int PCAP, int RELU, int EPI, int NOUT, int ARAW>
__global__ __launch_bounds__(256)
void gemm_kernel(const u16* A0, const u16* A1, const u16* A2,
                 const u16* W0, const u16* W1, const u16* W2,
                 const float* __restrict__ bias, const float* __restrict__ c2p,
                 u16* O0, u16* O1, u16* O2,
                 float* outf, void* dout, size_t doff,
                 const u32* __restrict__ flag, int M, int N, int K)
{
  __shared__ __align__(16) u16 lds[(NA + NW) * 4096];
  const u32 fm = flag[0];
  if (fm)
    gemm_body<NA, NW, PCAP, RELU, EPI, NOUT>(A0, A1, A2, W0, W1, W2, bias, c2p,
                                             O0, O1, O2, outf, dout, doff, fm, M, N, K, lds);
  else
    gemm_body<(ARAW ? 1 : NA), 1, PCAP, RELU, EPI, NOUT>(A0, A1, A2, W0, W1, W2, bias, c2p,
                                             O0, O1, O2, outf, dout, doff, fm, M, N, K, lds);
}

// ======================= 8-phase 256-wide kernel (big layers) =======================
// Plane passes folded into K' = NPASS*K (pass-indexed plane pointers per K-tile).
// BK=64, 8 waves (512 thr), double-buffered LDS, st_16x32 XOR swizzle via
// pre-swizzled global source + swizzled ds_read (linear global_load_lds dest),
// counted vmcnt (2 tiles in flight), setprio around MFMA quadrants, XCD swizzle.

template<int NPASS, int PSET, int WN, int WTM, int WTN, int HB, int RELU, int EPI, int NOUT>
__device__ __forceinline__ void gemm8_body(
    const u16* __restrict__ A0, const u16* __restrict__ A1, const u16* __restrict__ A2,
    const u16* __restrict__ W0, const u16* __restrict__ W1, const u16* __restrict__ W2,
    const float* __restrict__ bias, const float* __restrict__ c2p,
    u16* __restrict__ O0, u16* __restrict__ O1, u16* __restrict__ O2,
    float* __restrict__ outf, void* __restrict__ dout, size_t doff,
    u32 fm, int M, int N, int K, u16* lds)
{
  constexpr int BN    = WN * WTN * 16;
  constexpr int HALV  = 2 + HB;          // A halves (2) + B halves
  constexpr int BUF   = HALV * 8192;     // u16 per buffer
  constexpr int UNITS = HALV * 2;        // global_load_lds per thread per K-tile
  constexpr int MH = WTM / 2, NH = WTN / 2;

  const int tid  = threadIdx.x;
  const int lane = tid & 63;
  const int wid  = tid >> 6;
  const int wc   = wid % WN;
  const int wr   = wid / WN;

  // XCD-aware bijective swizzle (m204 formula)
  const int gx = gridDim.x, gy = gridDim.y;
  const int nwg = gx * gy;
  const int f0 = blockIdx.y * gx + blockIdx.x;
  const int qq = nwg >> 3, rr = nwg & 7;
  const int xcd = f0 & 7, lin = f0 >> 3;
  const int sw = (xcd < rr ? xcd * (qq + 1) : rr * (qq + 1) + (xcd - rr) * qq) + lin;
  const int bx = sw % gx;
  const int by = sw / gx;
  const int m0 = by * 256;
  const int n0 = bx * BN;

  const int kt  = K >> 6;                 // K-tiles per pass (pow2)
  const int ksh = __builtin_ctz(kt);
  const int nt  = NPASS * kt;

  auto stage_half = [&](u16* region, const u16* src, int Kst) {
    #pragma unroll
    for (int c = 0; c < 2; ++c) {
      int ci = wid * 128 + c * 64 + lane;          // 16B chunk 0..1023
      int Lb = ci * 16;                            // linear byte in half
      int T  = Lb ^ (((Lb >> 9) & 1) << 5);        // inverse-swizzled source byte
      int row = T >> 7, col = T & 127;
      const char* s = (const char*)src + (size_t)row * ((size_t)Kst * 2) + col;
      u16* dst = region + (size_t)(wid * 128 + c * 64) * 8;   // wave-uniform, linear
      __builtin_amdgcn_global_load_lds(
          (const __attribute__((address_space(1))) void*)s,
          (__attribute__((address_space(3))) void*)dst, 16, 0, 0);
    }
  };

  auto stage_tile = [&](int buf, int t) {
    int p = t >> ksh;
    int k0 = (t & (kt - 1)) << 6;
    constexpr int PAm[6] = {0, 0, 1, 1, 0, 2};
    constexpr int PWm[6] = {0, 1, 0, 1, 2, 0};
    int pa = 0, pw = 0;
    #pragma unroll
    for (int q = 0; q < NPASS; ++q)
      if (p == q) { pa = (PSET == 0) ? PAm[q] : q; pw = (PSET == 0) ? PWm[q] : 0; }
    const u16* Ab = (pa == 0) ? A0 : ((pa == 1) ? A1 : A2);
    const u16* Wb = (pw == 0) ? W0 : ((pw == 1) ? W1 : W2);
    u16* base = lds + buf * BUF;
    #pragma unroll
    for (int h = 0; h < 2; ++h)
      stage_half(base + h * 8192, Ab + (size_t)(m0 + h * 128) * K + k0, K);
    #pragma unroll
    for (int h = 0; h < HB; ++h)
      stage_half(base + (2 + h) * 8192, Wb + (size_t)(n0 + h * 128) * K + k0, K);
  };

  auto rdfrag = [&](const u16* region, int rho, int kk) -> short8 {
    int L = rho * 128 + kk * 64 + ((lane >> 4) * 16);
    L ^= ((L >> 9) & 1) << 5;                      // same involution as staging
    return *(const short8*)((const char*)region + L);
  };

  f32x4 acc[WTM][WTN];
  #pragma unroll
  for (int i = 0; i < WTM; ++i)
    #pragma unroll
    for (int j = 0; j < WTN; ++j)
      acc[i][j] = f32x4{0.f, 0.f, 0.f, 0.f};

  stage_tile(0, 0);
  stage_tile(1, 1);
  int cur = 0;

  const int ha = (wr * WTM * 16) >> 7;
  const int ra = (wr * WTM * 16) & 127;
  const int hbb = (wc * WTN * 16) >> 7;
  const int rb = (wc * WTN * 16) & 127;

  for (int t = 0; t < nt; ++t) {
    if (t < nt - 1) asm volatile("s_waitcnt vmcnt(%0)" :: "i"(UNITS) : "memory");
    else            asm volatile("s_waitcnt vmcnt(0)" ::: "memory");
    __builtin_amdgcn_s_barrier();
    __builtin_amdgcn_sched_barrier(0);

    const u16* bufb = lds + cur * BUF;
    const u16* areg = bufb + ha * 8192;
    const u16* breg = bufb + (2 + hbb) * 8192;

    short8 afr[MH][2], bfr0[NH][2], bfr1[NH][2];

    // phase 1: A-sub0 + B-sub0 -> Q0
    #pragma unroll
    for (int i = 0; i < MH; ++i)
      #pragma unroll
      for (int kk = 0; kk < 2; ++kk)
        afr[i][kk] = rdfrag(areg, ra + i * 16 + (lane & 15), kk);
    #pragma unroll
    for (int j = 0; j < NH; ++j)
      #pragma unroll
      for (int kk = 0; kk < 2; ++kk)
        bfr0[j][kk] = rdfrag(breg, rb + j * 16 + (lane & 15), kk);
    __builtin_amdgcn_s_setprio(1);
    #pragma unroll
    for (int i = 0; i < MH; ++i)
      #pragma unroll
      for (int j = 0; j < NH; ++j)
        #pragma unroll
        for (int kk = 0; kk < 2; ++kk)
          acc[i][j] = __builtin_amdgcn_mfma_f32_16x16x32_bf16(
              afr[i][kk], bfr0[j][kk], acc[i][j], 0, 0, 0);
    __builtin_amdgcn_s_setprio(0);

    // phase 2: B-sub1 -> Q1
    #pragma unroll
    for (int j = 0; j < NH; ++j)
      #pragma unroll
      for (int kk = 0; kk < 2; ++kk)
        bfr1[j][kk] = rdfrag(breg, rb + (NH + j) * 16 + (lane & 15), kk);
    __builtin_amdgcn_s_setprio(1);
    #pragma unroll
    for (int i = 0; i < MH; ++i)
      #pragma unroll
      for (int j = 0; j < NH; ++j)
        #pragma unroll
        for (int kk = 0; kk < 2; ++kk)
          acc[i][NH + j] = __builtin_amdgcn_mfma_f32_16x16x32_bf16(
              afr[i][kk], bfr1[j][kk], acc[i][NH + j], 0, 0, 0);
    __builtin_amdgcn_s_setprio(0);

    // phase 3: A-sub1 (reuse afr) -> Q2
    #pragma unroll
    for (int i = 0; i < MH; ++i)
      #pragma unroll
      for (int kk = 0; kk < 2; ++kk)
        afr[i][kk] = rdfrag(areg, ra + (MH + i) * 16 + (lane & 15), kk);
    __builtin_amdgcn_s_setprio(1);
    #pragma unroll
    for (int i = 0; i < MH; ++i)
      #pragma unroll
      for (int j = 0; j < NH; ++j)
        #pragma unroll
        for (int kk = 0; kk < 2; ++kk)
          acc[MH + i][j] = __builtin_amdgcn_mfma_f32_16x16x32_bf16(
              afr[i][kk], bfr0[j][kk], acc[MH + i][j], 0, 0, 0);
    __builtin_amdgcn_s_setprio(0);

    // all of this wave's ds_reads from buf are retired; join, then overwrite buf
    asm volatile("s_waitcnt lgkmcnt(0)" ::: "memory");
    __builtin_amdgcn_s_barrier();
    __builtin_amdgcn_sched_barrier(0);
    if (t + 2 < nt) stage_tile(cur, t + 2);
    __builtin_amdgcn_sched_barrier(0);

    // phase 4: Q3 (register-only; overlaps the DMA just issued)
    __builtin_amdgcn_s_setprio(1);
    #pragma unroll
    for (int i = 0; i < MH; ++i)
      #pragma unroll
      for (int j = 0; j < NH; ++j)
        #pragma unroll
        for (int kk = 0; kk < 2; ++kk)
          acc[MH + i][NH + j] = __builtin_amdgcn_mfma_f32_16x16x32_bf16(
              afr[i][kk], bfr1[j][kk], acc[MH + i][NH + j], 0, 0, 0);
    __builtin_amdgcn_s_setprio(0);
    cur ^= 1;
  }

  // epilogue (same C/D layout as 128 kernel)
  #pragma unroll
  for (int i = 0; i < WTM; ++i) {
    int rbase = m0 + wr * WTM * 16 + i * 16 + ((lane >> 4) * 4);
    #pragma unroll
    for (int j = 0; j < WTN; ++j) {
      int col = n0 + wc * WTN * 16 + j * 16 + (lane & 15);
      float bv = 0.f, c2v = 0.f;
      if (EPI != EPI_SCORES) bv = bias[col];
      if (EPI == EPI_SCORES) c2v = c2p[col];
      #pragma unroll
      for (int r = 0; r < 4; ++r) {
        float v = acc[i][j][r] + bv;
        if (RELU) v = fmaxf(v, 0.f);
        size_t idx = (size_t)(rbase + r) * N + col;
        if (EPI == EPI_SCORES) {
          outf[idx] = c2v - 2.f * v;
        } else {
          if (NOUT >= 1) {
            u16 h = f2bf(v);
            O0[idx] = h;
            if (NOUT >= 2) {
              float r1 = v - bf2f(h);
              u16 m = f2bf(r1);
              O1[idx] = m;
              if (NOUT >= 3) O2[idx] = f2bf(r1 - bf2f(m));
            }
          }
          if (EPI == EPI_EMB || EPI == EPI_OUT) mode_store(dout, doff + idx, v, fm);
        }
      }
    }
  }
}

// CFG 0: 256x256 (WN=4, wave 128x64, LDS 128KB). CFG 1: 256x128 (WN=2, wave 64x64, 96KB).
template<int CFG, int NP32, int NPBF, int RELU, int EPI, int NOUT>
__global__ __launch_bounds__(512, 2)
void gemm8_kernel(const u16* A0, const u16* A1, const u16* A2,
                  const u16* W0, const u16* W1, const u16* W2,
                  const float* __restrict__ bias, const float* __restrict__ c2p,
                  u16* O0, u16* O1, u16* O2,
                  float* outf, void* dout, size_t doff,
                  const u32* __restrict__ flag, int M, int N, int K)
{
  constexpr int WN  = (CFG == 0) ? 4 : 2;
  constexpr int WTM = (CFG == 0) ? 8 : 4;
  constexpr int HB  = (CFG == 0) ? 2 : 1;
  __shared__ __align__(16) u16 lds[(2 + HB) * 8192 * 2];
  const u32 fm = flag[0];
  if (fm)
    gemm8_body<NP32, 0, WN, WTM, 4, HB, RELU, EPI, NOUT>(
        A0, A1, A2, W0, W1, W2, bias, c2p, O0, O1, O2, outf, dout, doff, fm, M, N, K, lds);
  else
    gemm8_body<NPBF, 1, WN, WTM, 4, HB, RELU, EPI, NOUT>(
        A0, A1, A2, W0, W1, W2, bias, c2p, O0, O1, O2, outf, dout, doff, fm, M, N, K, lds);
}

// per-row argmin over K=1024 (np first-index tie-break) -> one-hot at d_out element offset
__global__ void argmin_onehot(const float* __restrict__ scores, void* __restrict__ dout,
                              size_t doff, const u32* __restrict__ flag) {
  const int Kc = 1024;
  u32 fm  = flag[0];
  int row  = blockIdx.x * 4 + (threadIdx.x >> 6);
  int lane = threadIdx.x & 63;
  const float* s = scores + (size_t)row * Kc;
  float bestv = 3.4e38f;
  int   besti = Kc;
  #pragma unroll
  for (int base = 0; base < Kc; base += 256) {
    float4 v = *(const float4*)&s[base + lane * 4];
    int i0 = base + lane * 4;
    if (v.x < bestv) { bestv = v.x; besti = i0; }
    if (v.y < bestv) { bestv = v.y; besti = i0 + 1; }
    if (v.z < bestv) { bestv = v.z; besti = i0 + 2; }
    if (v.w < bestv) { bestv = v.w; besti = i0 + 3; }
  }
  #pragma unroll
  for (int off = 32; off; off >>= 1) {
    float ov = __shfl_down(bestv, off);
    int   oi = __shfl_down(besti, off);
    if (ov < bestv || (ov == bestv && oi < besti)) { bestv = ov; besti = oi; }
  }
  besti = __shfl(besti, 0);
  size_t eb = doff + (size_t)row * Kc + lane * 16;
  if (fm) {
    float* op = (float*)dout;
    #pragma unroll
    for (int q = 0; q < 16; ++q)
      op[eb + q] = (lane * 16 + q == besti) ? 1.0f : 0.0f;
  } else {
    u16* op = (u16*)dout + eb;
    uint32_t w[8];
    #pragma unroll
    for (int q = 0; q < 8; ++q) {
      int c0 = lane * 16 + q * 2;
      w[q] = ((c0 == besti) ? 0x3F80u : 0u) | (((c0 + 1 == besti) ? 0x3F80u : 0u) << 16);
    }
    *(uint4*)op       = make_uint4(w[0], w[1], w[2], w[3]);
    *(uint4*)(op + 8) = make_uint4(w[4], w[5], w[6], w[7]);
  }
}

extern "C" void kernel_launch(void* const* d_in, const int* in_sizes, int n_in,
                              void* d_out, int out_size, void* d_ws, size_t ws_size,
                              hipStream_t stream) {
  const int Bn = 8192;
  const int ENC[5] = {1024, 2048, 1024, 512, 256};
  const int DEC[5] = {256, 512, 1024, 2048, 1024};

  const void* x = d_in[0];
  const void *We[4], *be[4], *Wd[4], *bd[4];
  for (int i = 0; i < 4; ++i) { We[i] = d_in[1 + 2 * i]; be[i] = d_in[2 + 2 * i]; }
  for (int i = 0; i < 4; ++i) { Wd[i] = d_in[9 + 2 * i]; bd[i] = d_in[10 + 2 * i]; }
  const void* centers = d_in[17];

  // ---- fixed workspace carve ----
  char* wsb = (char*)d_ws;
  size_t o = 0;
  auto carve = [&](size_t bytes) { void* p = wsb + o; o += (bytes + 63) & ~size_t(63); return p; };
  u32* flag = (u32*)carve(64);
  u16 *WTe[4][3], *WTd[4][3];
  for (int i = 0; i < 4; ++i)
    for (int p = 0; p < 3; ++p) WTe[i][p] = (u16*)carve((size_t)ENC[i] * ENC[i + 1] * 2);
  for (int i = 0; i < 4; ++i)
    for (int p = 0; p < 3; ++p) WTd[i][p] = (u16*)carve((size_t)DEC[i] * DEC[i + 1] * 2);
  float* bef[4]; float* bdf[4];
  for (int i = 0; i < 4; ++i) bef[i] = (float*)carve((size_t)ENC[i + 1] * 4);
  for (int i = 0; i < 4; ++i) bdf[i] = (float*)carve((size_t)DEC[i + 1] * 4);
  float* cenf = (float*)carve(1024 * 256 * 4);
  u16* cen[3];
  for (int p = 0; p < 3; ++p) cen[p] = (u16*)carve(1024 * 256 * 2);
  float* c2 = (float*)carve(1024 * 4);

  // ---- chunk size from remaining ws; per-chunk activation planes: 29184 B/row ----
  size_t rem = (ws_size > o) ? ws_size - o - 4096 : 0;
  int CH = 256;
  for (int c = 8192; c >= 256; c >>= 1)
    if ((size_t)c * 29184 <= rem) { CH = c; break; }
  const int nch = Bn / CH;

  u16* xp[3];  for (int p = 0; p < 3; ++p) xp[p]  = (u16*)carve((size_t)CH * 1024 * 2);
  u16* h1p[3]; for (int p = 0; p < 3; ++p) h1p[p] = (u16*)carve((size_t)CH * 2048 * 2);
  u16* h2p[3]; for (int p = 0; p < 3; ++p) h2p[p] = (u16*)carve((size_t)CH * 1024 * 2);
  u16* h3p[3]; for (int p = 0; p < 3; ++p) h3p[p] = (u16*)carve((size_t)CH * 512 * 2);
  u16* ep[3];  for (int p = 0; p < 3; ++p) ep[p]  = (u16*)carve((size_t)CH * 256 * 2);
  // overlays (stream-ordered reuse of dead regions):
  float* scores = (float*)xp[0];            // CH*4096 B <= xp region CH*6144; xp dead after L0
  char* dreg = (char*)h1p[0];               // h1p+h2p region: CH*18432 B, dead after L1/L2
  u16* g1p[2] = {(u16*)dreg,                        (u16*)(dreg + (size_t)CH * 1024)};
  u16* g2p[2] = {(u16*)(dreg + (size_t)CH * 2048),  (u16*)(dreg + (size_t)CH * 4096)};
  u16* g3p[2] = {(u16*)(dreg + (size_t)CH * 6144),  (u16*)(dreg + (size_t)CH * 10240)};

  const size_t off_emb    = (size_t)Bn * 1024;
  const size_t off_labels = (size_t)Bn * 1280;

  // ---- prep: detect dtype, convert/transpose/decompose params ----
  detect_kernel<<<1, 256, 0, stream>>>((const u32*)x, flag);
  for (int i = 0; i < 4; ++i)
    trans_decomp_kernel<<<dim3(ENC[i + 1] / 32, ENC[i] / 32), 256, 0, stream>>>(
        We[i], WTe[i][0], WTe[i][1], WTe[i][2], ENC[i], ENC[i + 1], flag);
  for (int i = 0; i < 4; ++i)
    trans_decomp_kernel<<<dim3(DEC[i + 1] / 32, DEC[i] / 32), 256, 0, stream>>>(
        Wd[i], WTd[i][0], WTd[i][1], WTd[i][2], DEC[i], DEC[i + 1], flag);
  for (int i = 0; i < 4; ++i) {
    convert_kernel<<<(ENC[i + 1] + 255) / 256, 256, 0, stream>>>(be[i], bef[i], ENC[i + 1], flag);
    convert_kernel<<<(DEC[i + 1] + 255) / 256, 256, 0, stream>>>(bd[i], bdf[i], DEC[i + 1], flag);
  }
  convert_kernel<<<(1024 * 256) / 256, 256, 0, stream>>>(centers, cenf, 1024 * 256, flag);
  decomp_kernel<<<(1024 * 256) / 256, 256, 0, stream>>>(cenf, cen[0], cen[1], cen[2], 1024 * 256);
  c2_kernel<<<256, 256, 0, stream>>>(cenf, c2);

  const int GY  = CH / 128;   // 128-tile grid rows
  const int GY2 = CH / 256;   // 256-tile grid rows
  for (int c = 0; c < nch; ++c) {
    decomp_x_kernel<<<(CH * 1024) / 256, 256, 0, stream>>>(
        x, xp[0], xp[1], xp[2], CH * 1024, (size_t)c * CH * 1024, flag);

    // encoder L0: 256x256 tile, K' = 6*1024 (fp32) / 1*1024 (bf16, x exact)
    gemm8_kernel<0, 6, 1, 1, EPI_PLANES, 3><<<dim3(2048 / 256, GY2), 512, 0, stream>>>(
        xp[0], xp[1], xp[2], WTe[0][0], WTe[0][1], WTe[0][2], bef[0], nullptr,
        h1p[0], h1p[1], h1p[2], nullptr, nullptr, 0, flag, CH, 2048, 1024);
    // encoder L1: 256x128 tile
    gemm8_kernel<1, 6, 3, 1, EPI_PLANES, 3><<<dim3(1024 / 128, GY2), 512, 0, stream>>>(
        h1p[0], h1p[1], h1p[2], WTe[1][0], WTe[1][1], WTe[1][2], bef[1], nullptr,
        h2p[0], h2p[1], h2p[2], nullptr, nullptr, 0, flag, CH, 1024, 2048);
    // encoder L2/L3: 128 kernel
    gemm_kernel<3, 3, 2, 1, EPI_PLANES, 3, 0><<<dim3(4, GY), 256, 0, stream>>>(
        h2p[0], h2p[1], h2p[2], WTe[2][0], WTe[2][1], WTe[2][2], bef[2], nullptr,
        h3p[0], h3p[1], h3p[2], nullptr, nullptr, 0, flag, CH, 512, 1024);
    gemm_kernel<3, 3, 2, 0, EPI_EMB, 3, 0><<<dim3(2, GY), 256, 0, stream>>>(
        h3p[0], h3p[1], h3p[2], WTe[3][0], WTe[3][1], WTe[3][2], bef[3], nullptr,
        ep[0], ep[1], ep[2], nullptr, d_out, off_emb + (size_t)c * CH * 256,
        flag, CH, 256, 512);

    // scores + labels
    gemm_kernel<3, 3, 2, 0, EPI_SCORES, 0, 0><<<dim3(8, GY), 256, 0, stream>>>(
        ep[0], ep[1], ep[2], cen[0], cen[1], cen[2], nullptr, c2,
        nullptr, nullptr, nullptr, scores, nullptr, 0, flag, CH, 1024, 256);
    argmin_onehot<<<CH / 4, 256, 0, stream>>>(scores, d_out,
        off_labels + (size_t)c * CH * 1024, flag);

    // decoder D0/D1: 128 kernel
    gemm_kernel<2, 2, 1, 1, EPI_PLANES, 2, 0><<<dim3(4, GY), 256, 0, stream>>>(
        ep[0], ep[1], nullptr, WTd[0][0], WTd[0][1], nullptr, bdf[0], nullptr,
        g1p[0], g1p[1], nullptr, nullptr, nullptr, 0, flag, CH, 512, 256);
    gemm_kernel<2, 2, 1, 1, EPI_PLANES, 2, 0><<<dim3(8, GY), 256, 0, stream>>>(
        g1p[0], g1p[1], nullptr, WTd[1][0], WTd[1][1], nullptr, bdf[1], nullptr,
        g2p[0], g2p[1], nullptr, nullptr, nullptr, 0, flag, CH, 1024, 512);
    // decoder D2: 256x256 tile, K' = 3*1024 (fp32) / 2*1024 (bf16)
    gemm8_kernel<0, 3, 2, 1, EPI_PLANES, 2><<<dim3(2048 / 256, GY2), 512, 0, stream>>>(
        g2p[0], g2p[1], nullptr, WTd[2][0], WTd[2][1], nullptr, bdf[2], nullptr,
        g3p[0], g3p[1], nullptr, nullptr, nullptr, 0, flag, CH, 2048, 1024);
    // decoder D3: 256x128 tile, final output
    gemm8_kernel<1, 3, 2, 0, EPI_OUT, 0><<<dim3(1024 / 128, GY2), 512, 0, stream>>>(
        g3p[0], g3p[1], nullptr, WTd[3][0], WTd[3][1], nullptr, bdf[3], nullptr,
        nullptr, nullptr, nullptr, nullptr, d_out, (size_t)c * CH * 1024,
        flag, CH, 1024, 2048);
  }

  (void)in_sizes; (void)n_in; (void)out_size;
}

// Round 3
// 976.056 us; speedup vs baseline: 2.4656x; 2.4656x over previous
//
#include <hip/hip_runtime.h>
#include <stdint.h>

typedef unsigned short u16;
typedef uint32_t u32;
typedef __attribute__((ext_vector_type(8))) short short8;
typedef __attribute__((ext_vector_type(4))) float f32x4;

__device__ __forceinline__ float bf2f(u16 v) {
  union { u32 u; float f; } c; c.u = ((u32)v) << 16; return c.f;
}
__device__ __forceinline__ u16 f2bf(float f) {
  union { float f; u32 u; } c; c.f = f;
  u32 r = c.u + 0x7fffu + ((c.u >> 16) & 1u);  // RNE
  return (u16)(r >> 16);
}
__device__ __forceinline__ void mode_store(void* p, size_t idx, float v, u32 fm) {
  if (fm) ((float*)p)[idx] = v;
  else    ((u16*)p)[idx]   = f2bf(v);
}

enum { EPI_PLANES = 0, EPI_EMB = 1, EPI_SCORES = 2, EPI_OUT = 3 };

// ---- dtype detection: low u16 of fp32 data is random mantissa bits -> wild bf16 ----
__global__ void detect_kernel(const u32* __restrict__ x, u32* __restrict__ flag) {
  __shared__ int cnt;
  if (threadIdx.x == 0) cnt = 0;
  __syncthreads();
  int wild = 0;
  #pragma unroll
  for (int c = 0; c < 4; ++c) {
    u32 u = x[threadIdx.x * 4 + c];
    float a = fabsf(bf2f((u16)(u & 0xffff)));
    if (!(a <= 1e6f) || (a != 0.f && a < 1e-20f)) wild++;  // !(a<=..) catches NaN
  }
  atomicAdd(&cnt, wild);
  __syncthreads();
  if (threadIdx.x == 0) flag[0] = (cnt > 100) ? 1u : 0u;  // 1 = fp32 inputs
}

// ---- canonicalize any input array to f32 (biases, centers) ----
__global__ void convert_kernel(const void* __restrict__ in, float* __restrict__ out,
                               int n, const u32* __restrict__ flag) {
  int i = blockIdx.x * 256 + threadIdx.x;
  if (i >= n) return;
  u32 fm = flag[0];
  out[i] = fm ? ((const float*)in)[i] : bf2f(((const u16*)in)[i]);
}

// ---- W[R=K][C=N] raw -> WT[N][K] in 3 bf16 planes (hi/mid/lo) ----
__global__ void trans_decomp_kernel(const void* __restrict__ in,
                                    u16* __restrict__ hi, u16* __restrict__ mid,
                                    u16* __restrict__ lo, int R, int C,
                                    const u32* __restrict__ flag) {
  __shared__ float t[32][33];
  u32 fm = flag[0];
  int x  = threadIdx.x & 31;
  int yq = threadIdx.x >> 5;
  int bx = blockIdx.x, by = blockIdx.y;
  #pragma unroll
  for (int yy = yq; yy < 32; yy += 8) {
    size_t src = (size_t)(by * 32 + yy) * C + bx * 32 + x;
    t[yy][x] = fm ? ((const float*)in)[src] : bf2f(((const u16*)in)[src]);
  }
  __syncthreads();
  #pragma unroll
  for (int yy = yq; yy < 32; yy += 8) {
    float v = t[x][yy];
    u16 h = f2bf(v);
    float r1 = v - bf2f(h);
    u16 m = f2bf(r1);
    u16 l = f2bf(r1 - bf2f(m));
    size_t dst = (size_t)(bx * 32 + yy) * R + by * 32 + x;
    hi[dst] = h; mid[dst] = m; lo[dst] = l;
  }
}

// ---- centers f32 -> 3 bf16 planes (same [K][D] layout, already B^T form) ----
__global__ void decomp_kernel(const float* __restrict__ in, u16* __restrict__ hi,
                              u16* __restrict__ mid, u16* __restrict__ lo, int n) {
  int i = blockIdx.x * 256 + threadIdx.x;
  if (i >= n) return;
  float v = in[i];
  u16 h = f2bf(v);
  float r1 = v - bf2f(h);
  u16 m = f2bf(r1);
  hi[i] = h; mid[i] = m; lo[i] = f2bf(r1 - bf2f(m));
}

// ---- c2[k] = sum_d centers[k][d]^2, from f32 centers, D=256 K=1024 ----
__global__ void c2_kernel(const float* __restrict__ cf, float* __restrict__ c2) {
  int w    = blockIdx.x * 4 + (threadIdx.x >> 6);
  int lane = threadIdx.x & 63;
  float4 v = *(const float4*)&cf[(size_t)w * 256 + lane * 4];
  float s = v.x * v.x + v.y * v.y + v.z * v.z + v.w * v.w;
  #pragma unroll
  for (int off = 32; off; off >>= 1) s += __shfl_down(s, off);
  if (lane == 0) c2[w] = s;
}

// ---- x chunk -> 3 bf16 planes (with element offset; dtype handled device-side) ----
__global__ void decomp_x_kernel(const void* __restrict__ in, u16* __restrict__ hi,
                                u16* __restrict__ mid, u16* __restrict__ lo,
                                int n, size_t eoff, const u32* __restrict__ flag) {
  int i = blockIdx.x * 256 + threadIdx.x;
  if (i >= n) return;
  u32 fm = flag[0];
  float v = fm ? ((const float*)in)[eoff + i] : bf2f(((const u16*)in)[eoff + i]);
  u16 h = f2bf(v);
  float r1 = v - bf2f(h);
  u16 m = f2bf(r1);
  hi[i] = h; mid[i] = m; lo[i] = f2bf(r1 - bf2f(m));
}

// ---- async stage of one 128x32 bf16 tile (8KB) into LDS via global_load_lds ----
__device__ __forceinline__ void stage_tile128(const u16* __restrict__ g, u16* lbase,
                                              int Kst, int tid) {
  const int lane = tid & 63;
  const int wv   = tid >> 6;
  #pragma unroll
  for (int c = 0; c < 2; ++c) {
    const int li   = wv * 128 + c * 64 + lane;   // 16B-chunk index, 0..511
    const int row  = li >> 2;
    const int colb = (li & 3) * 16;
    const char* src = (const char*)g + (size_t)row * ((size_t)Kst * 2) + colb;
    u16* dst = lbase + (size_t)(wv * 128 + c * 64) * 8;  // wave-uniform
    __builtin_amdgcn_global_load_lds(
        (const __attribute__((address_space(1))) void*)src,
        (__attribute__((address_space(3))) void*)dst, 16, 0, 0);
  }
}

// Fully static GEMM body: C = act(sum_{pa+pw<=PCAP} Aplane[pa] @ Wplane[pw]^T + bias).
// 128x128 tile, BK=32, 4 waves, 4x4 MFMA 16x16x32 per wave (m92/m97 layout).
// XCD-chunked bijective block swizzle (bx-fast stripes): each XCD owns a
// contiguous row-stripe of output tiles -> A panels read from ONE XCD's L2,
// W panels shared within the stripe. Identity when nwg%8!=0 (bijectivity, m204).
template<int nA, int nW, int PCAP, int RELU, int EPI, int NOUT>
__device__ __forceinline__ void gemm_body(
    const u16* __restrict__ A0, const u16* __restrict__ A1, const u16* __restrict__ A2,
    const u16* __restrict__ W0, const u16* __restrict__ W1, const u16* __restrict__ W2,
    const float* __restrict__ bias, const float* __restrict__ c2p,
    u16* __restrict__ O0, u16* __restrict__ O1, u16* __restrict__ O2,
    float* __restrict__ outf, void* __restrict__ dout, size_t doff,
    u32 fm, int M, int N, int K, u16* lds)
{
  const int tid  = threadIdx.x;
  const int lane = tid & 63;
  const int wid  = tid >> 6;

  const int gx = gridDim.x, gy = gridDim.y;
  const int nwg = gx * gy;
  int bx = blockIdx.x, by = blockIdx.y;
  if ((nwg & 7) == 0) {
    int f0 = by * gx + bx;
    int sw = (f0 & 7) * (nwg >> 3) + (f0 >> 3);
    bx = sw % gx; by = sw / gx;
  }
  const int m0 = by * 128;
  const int n0 = bx * 128;
  const int wm = (wid & 1) * 64;
  const int wn = (wid >> 1) * 64;
  const u16* Ap[3] = {A0, A1, A2};
  const u16* Wp[3] = {W0, W1, W2};

  f32x4 acc[4][4];
  #pragma unroll
  for (int i = 0; i < 4; ++i)
    #pragma unroll
    for (int j = 0; j < 4; ++j)
      acc[i][j] = f32x4{0.f, 0.f, 0.f, 0.f};

  for (int k0 = 0; k0 < K; k0 += 32) {
    __syncthreads();
    #pragma unroll
    for (int p = 0; p < nA; ++p)
      stage_tile128(Ap[p] + (size_t)m0 * K + k0, lds + p * 4096, K, tid);
    #pragma unroll
    for (int q = 0; q < nW; ++q)
      stage_tile128(Wp[q] + (size_t)n0 * K + k0, lds + (nA + q) * 4096, K, tid);
    __syncthreads();

    short8 bfrag[nW][4];
    #pragma unroll
    for (int q = 0; q < nW; ++q)
      #pragma unroll
      for (int j = 0; j < 4; ++j) {
        int r = wn + j * 16 + (lane & 15);
        bfrag[q][j] = *(const short8*)&lds[(nA + q) * 4096 + r * 32 + (lane >> 4) * 8];
      }
    #pragma unroll
    for (int pa = 0; pa < nA; ++pa) {
      short8 afrag[4];
      #pragma unroll
      for (int i = 0; i < 4; ++i) {
        int r = wm + i * 16 + (lane & 15);
        afrag[i] = *(const short8*)&lds[pa * 4096 + r * 32 + (lane >> 4) * 8];
      }
      #pragma unroll
      for (int pw = 0; pw < nW; ++pw) {
        if (pa + pw <= PCAP) {
          #pragma unroll
          for (int i = 0; i < 4; ++i)
            #pragma unroll
            for (int j = 0; j < 4; ++j)
              acc[i][j] = __builtin_amdgcn_mfma_f32_16x16x32_bf16(
                  afrag[i], bfrag[pw][j], acc[i][j], 0, 0, 0);
        }
      }
    }
  }

  // epilogue: C/D layout col=lane&15, row=(lane>>4)*4+reg
  #pragma unroll
  for (int i = 0; i < 4; ++i) {
    int rbase = m0 + wm + i * 16 + ((lane >> 4) * 4);
    #pragma unroll
    for (int j = 0; j < 4; ++j) {
      int col = n0 + wn + j * 16 + (lane & 15);
      float bv = 0.f, c2v = 0.f;
      if (EPI != EPI_SCORES) bv = bias[col];
      if (EPI == EPI_SCORES) c2v = c2p[col];
      #pragma unroll
      for (int r = 0; r < 4; ++r) {
        float v = acc[i][j][r] + bv;
        if (RELU) v = fmaxf(v, 0.f);
        size_t idx = (size_t)(rbase + r) * N + col;
        if (EPI == EPI_SCORES) {
          outf[idx] = c2v - 2.f * v;
        } else {
          if (NOUT >= 1) {
            u16 h = f2bf(v);
            O0[idx] = h;
            if (NOUT >= 2) {
              float r1 = v - bf2f(h);
              u16 m = f2bf(r1);
              O1[idx] = m;
              if (NOUT >= 3) O2[idx] = f2bf(r1 - bf2f(m));
            }
          }
          if (EPI == EPI_EMB || EPI == EPI_OUT) mode_store(dout, doff + idx, v, fm);
        }
      }
    }
  }
}

template<int NA, int NW, int PCAP, int RELU, int EPI, int NOUT, int ARAW>
__global__ __launch_bounds__(256)
void gemm_kernel(const u16* A0, const u16* A1, const u16* A2,
                 const u16* W0, const u16* W1, const u16* W2,
                 const float* __restrict__ bias, const float* __restrict__ c2p,
                 u16* O0, u16* O1, u16* O2,
                 float* outf, void* dout, size_t doff,
                 const u32* __restrict__ flag, int M, int N, int K)
{
  __shared__ __align__(16) u16 lds[(NA + NW) * 4096];
  const u32 fm = flag[0];
  if (fm)
    gemm_body<NA, NW, PCAP, RELU, EPI, NOUT>(A0, A1, A2, W0, W1, W2, bias, c2p,
                                             O0, O1, O2, outf, dout, doff, fm, M, N, K, lds);
  else
    gemm_body<(ARAW ? 1 : NA), 1, PCAP, RELU, EPI, NOUT>(A0, A1, A2, W0, W1, W2, bias, c2p,
                                             O0, O1, O2, outf, dout, doff, fm, M, N, K, lds);
}

// per-row argmin over K=1024 (np first-index tie-break) -> one-hot at d_out element offset
__global__ void argmin_onehot(const float* __restrict__ scores, void* __restrict__ dout,
                              size_t doff, const u32* __restrict__ flag) {
  const int Kc = 1024;
  u32 fm  = flag[0];
  int row  = blockIdx.x * 4 + (threadIdx.x >> 6);
  int lane = threadIdx.x & 63;
  const float* s = scores + (size_t)row * Kc;
  float bestv = 3.4e38f;
  int   besti = Kc;
  #pragma unroll
  for (int base = 0; base < Kc; base += 256) {
    float4 v = *(const float4*)&s[base + lane * 4];
    int i0 = base + lane * 4;
    if (v.x < bestv) { bestv = v.x; besti = i0; }
    if (v.y < bestv) { bestv = v.y; besti = i0 + 1; }
    if (v.z < bestv) { bestv = v.z; besti = i0 + 2; }
    if (v.w < bestv) { bestv = v.w; besti = i0 + 3; }
  }
  #pragma unroll
  for (int off = 32; off; off >>= 1) {
    float ov = __shfl_down(bestv, off);
    int   oi = __shfl_down(besti, off);
    if (ov < bestv || (ov == bestv && oi < besti)) { bestv = ov; besti = oi; }
  }
  besti = __shfl(besti, 0);
  size_t eb = doff + (size_t)row * Kc + lane * 16;
  if (fm) {
    float* op = (float*)dout;
    #pragma unroll
    for (int q = 0; q < 16; ++q)
      op[eb + q] = (lane * 16 + q == besti) ? 1.0f : 0.0f;
  } else {
    u16* op = (u16*)dout + eb;
    uint32_t w[8];
    #pragma unroll
    for (int q = 0; q < 8; ++q) {
      int c0 = lane * 16 + q * 2;
      w[q] = ((c0 == besti) ? 0x3F80u : 0u) | (((c0 + 1 == besti) ? 0x3F80u : 0u) << 16);
    }
    *(uint4*)op       = make_uint4(w[0], w[1], w[2], w[3]);
    *(uint4*)(op + 8) = make_uint4(w[4], w[5], w[6], w[7]);
  }
}

extern "C" void kernel_launch(void* const* d_in, const int* in_sizes, int n_in,
                              void* d_out, int out_size, void* d_ws, size_t ws_size,
                              hipStream_t stream) {
  const int Bn = 8192;
  const int ENC[5] = {1024, 2048, 1024, 512, 256};
  const int DEC[5] = {256, 512, 1024, 2048, 1024};

  const void* x = d_in[0];
  const void *We[4], *be[4], *Wd[4], *bd[4];
  for (int i = 0; i < 4; ++i) { We[i] = d_in[1 + 2 * i]; be[i] = d_in[2 + 2 * i]; }
  for (int i = 0; i < 4; ++i) { Wd[i] = d_in[9 + 2 * i]; bd[i] = d_in[10 + 2 * i]; }
  const void* centers = d_in[17];

  // ---- fixed workspace carve ----
  char* wsb = (char*)d_ws;
  size_t o = 0;
  auto carve = [&](size_t bytes) { void* p = wsb + o; o += (bytes + 63) & ~size_t(63); return p; };
  u32* flag = (u32*)carve(64);
  u16 *WTe[4][3], *WTd[4][3];
  for (int i = 0; i < 4; ++i)
    for (int p = 0; p < 3; ++p) WTe[i][p] = (u16*)carve((size_t)ENC[i] * ENC[i + 1] * 2);
  for (int i = 0; i < 4; ++i)
    for (int p = 0; p < 3; ++p) WTd[i][p] = (u16*)carve((size_t)DEC[i] * DEC[i + 1] * 2);
  float* bef[4]; float* bdf[4];
  for (int i = 0; i < 4; ++i) bef[i] = (float*)carve((size_t)ENC[i + 1] * 4);
  for (int i = 0; i < 4; ++i) bdf[i] = (float*)carve((size_t)DEC[i + 1] * 4);
  float* cenf = (float*)carve(1024 * 256 * 4);
  u16* cen[3];
  for (int p = 0; p < 3; ++p) cen[p] = (u16*)carve(1024 * 256 * 2);
  float* c2 = (float*)carve(1024 * 4);

  // ---- chunk size from remaining ws; per-chunk activation planes: 29184 B/row ----
  size_t rem = (ws_size > o) ? ws_size - o - 4096 : 0;
  int CH = 256;
  for (int c = 8192; c >= 256; c >>= 1)
    if ((size_t)c * 29184 <= rem) { CH = c; break; }
  const int nch = Bn / CH;

  u16* xp[3];  for (int p = 0; p < 3; ++p) xp[p]  = (u16*)carve((size_t)CH * 1024 * 2);
  u16* h1p[3]; for (int p = 0; p < 3; ++p) h1p[p] = (u16*)carve((size_t)CH * 2048 * 2);
  u16* h2p[3]; for (int p = 0; p < 3; ++p) h2p[p] = (u16*)carve((size_t)CH * 1024 * 2);
  u16* h3p[3]; for (int p = 0; p < 3; ++p) h3p[p] = (u16*)carve((size_t)CH * 512 * 2);
  u16* ep[3];  for (int p = 0; p < 3; ++p) ep[p]  = (u16*)carve((size_t)CH * 256 * 2);
  // overlays (stream-ordered reuse of dead regions):
  float* scores = (float*)xp[0];            // CH*4096 B <= xp region CH*6144; xp dead after L0
  char* dreg = (char*)h1p[0];               // h1p+h2p region: CH*18432 B, dead after L1/L2
  u16* g1p[2] = {(u16*)dreg,                        (u16*)(dreg + (size_t)CH * 1024)};
  u16* g2p[2] = {(u16*)(dreg + (size_t)CH * 2048),  (u16*)(dreg + (size_t)CH * 4096)};
  u16* g3p[2] = {(u16*)(dreg + (size_t)CH * 6144),  (u16*)(dreg + (size_t)CH * 10240)};

  const size_t off_emb    = (size_t)Bn * 1024;
  const size_t off_labels = (size_t)Bn * 1280;

  // ---- prep: detect dtype, convert/transpose/decompose params ----
  detect_kernel<<<1, 256, 0, stream>>>((const u32*)x, flag);
  for (int i = 0; i < 4; ++i)
    trans_decomp_kernel<<<dim3(ENC[i + 1] / 32, ENC[i] / 32), 256, 0, stream>>>(
        We[i], WTe[i][0], WTe[i][1], WTe[i][2], ENC[i], ENC[i + 1], flag);
  for (int i = 0; i < 4; ++i)
    trans_decomp_kernel<<<dim3(DEC[i + 1] / 32, DEC[i] / 32), 256, 0, stream>>>(
        Wd[i], WTd[i][0], WTd[i][1], WTd[i][2], DEC[i], DEC[i + 1], flag);
  for (int i = 0; i < 4; ++i) {
    convert_kernel<<<(ENC[i + 1] + 255) / 256, 256, 0, stream>>>(be[i], bef[i], ENC[i + 1], flag);
    convert_kernel<<<(DEC[i + 1] + 255) / 256, 256, 0, stream>>>(bd[i], bdf[i], DEC[i + 1], flag);
  }
  convert_kernel<<<(1024 * 256) / 256, 256, 0, stream>>>(centers, cenf, 1024 * 256, flag);
  decomp_kernel<<<(1024 * 256) / 256, 256, 0, stream>>>(cenf, cen[0], cen[1], cen[2], 1024 * 256);
  c2_kernel<<<256, 256, 0, stream>>>(cenf, c2);

  const int GY = CH / 128;
  for (int c = 0; c < nch; ++c) {
    decomp_x_kernel<<<(CH * 1024) / 256, 256, 0, stream>>>(
        x, xp[0], xp[1], xp[2], CH * 1024, (size_t)c * CH * 1024, flag);

    // encoder
    gemm_kernel<3, 3, 2, 1, EPI_PLANES, 3, 1><<<dim3(16, GY), 256, 0, stream>>>(
        xp[0], xp[1], xp[2], WTe[0][0], WTe[0][1], WTe[0][2], bef[0], nullptr,
        h1p[0], h1p[1], h1p[2], nullptr, nullptr, 0, flag, CH, 2048, 1024);
    gemm_kernel<3, 3, 2, 1, EPI_PLANES, 3, 0><<<dim3(8, GY), 256, 0, stream>>>(
        h1p[0], h1p[1], h1p[2], WTe[1][0], WTe[1][1], WTe[1][2], bef[1], nullptr,
        h2p[0], h2p[1], h2p[2], nullptr, nullptr, 0, flag, CH, 1024, 2048);
    gemm_kernel<3, 3, 2, 1, EPI_PLANES, 3, 0><<<dim3(4, GY), 256, 0, stream>>>(
        h2p[0], h2p[1], h2p[2], WTe[2][0], WTe[2][1], WTe[2][2], bef[2], nullptr,
        h3p[0], h3p[1], h3p[2], nullptr, nullptr, 0, flag, CH, 512, 1024);
    gemm_kernel<3, 3, 2, 0, EPI_EMB, 3, 0><<<dim3(2, GY), 256, 0, stream>>>(
        h3p[0], h3p[1], h3p[2], WTe[3][0], WTe[3][1], WTe[3][2], bef[3], nullptr,
        ep[0], ep[1], ep[2], nullptr, d_out, off_emb + (size_t)c * CH * 256,
        flag, CH, 256, 512);

    // scores + labels
    gemm_kernel<3, 3, 2, 0, EPI_SCORES, 0, 0><<<dim3(8, GY), 256, 0, stream>>>(
        ep[0], ep[1], ep[2], cen[0], cen[1], cen[2], nullptr, c2,
        nullptr, nullptr, nullptr, scores, nullptr, 0, flag, CH, 1024, 256);
    argmin_onehot<<<CH / 4, 256, 0, stream>>>(scores, d_out,
        off_labels + (size_t)c * CH * 1024, flag);

    // decoder
    gemm_kernel<2, 2, 1, 1, EPI_PLANES, 2, 0><<<dim3(4, GY), 256, 0, stream>>>(
        ep[0], ep[1], nullptr, WTd[0][0], WTd[0][1], nullptr, bdf[0], nullptr,
        g1p[0], g1p[1], nullptr, nullptr, nullptr, 0, flag, CH, 512, 256);
    gemm_kernel<2, 2, 1, 1, EPI_PLANES, 2, 0><<<dim3(8, GY), 256, 0, stream>>>(
        g1p[0], g1p[1], nullptr, WTd[1][0], WTd[1][1], nullptr, bdf[1], nullptr,
        g2p[0], g2p[1], nullptr, nullptr, nullptr, 0, flag, CH, 1024, 512);
    gemm_kernel<2, 2, 1, 1, EPI_PLANES, 2, 0><<<dim3(16, GY), 256, 0, stream>>>(
        g2p[0], g2p[1], nullptr, WTd[2][0], WTd[2][1], nullptr, bdf[2], nullptr,
        g3p[0], g3p[1], nullptr, nullptr, nullptr, 0, flag, CH, 2048, 1024);
    gemm_kernel<2, 2, 1, 0, EPI_OUT, 0, 0><<<dim3(8, GY), 256, 0, stream>>>(
        g3p[0], g3p[1], nullptr, WTd[3][0], WTd[3][1], nullptr, bdf[3], nullptr,
        nullptr, nullptr, nullptr, nullptr, d_out, (size_t)c * CH * 1024,
        flag, CH, 1024, 2048);
  }

  (void)in_sizes; (void)n_in; (void)out_size;
}

// Round 4
// 925.401 us; speedup vs baseline: 2.6005x; 1.0547x over previous
//
#include <hip/hip_runtime.h>
#include <stdint.h>

typedef unsigned short u16;
typedef uint32_t u32;
typedef __attribute__((ext_vector_type(8))) short short8;
typedef __attribute__((ext_vector_type(4))) float f32x4;

__device__ __forceinline__ float bf2f(u16 v) {
  union { u32 u; float f; } c; c.u = ((u32)v) << 16; return c.f;
}
__device__ __forceinline__ u16 f2bf(float f) {
  union { float f; u32 u; } c; c.f = f;
  u32 r = c.u + 0x7fffu + ((c.u >> 16) & 1u);  // RNE
  return (u16)(r >> 16);
}
__device__ __forceinline__ void mode_store(void* p, size_t idx, float v, u32 fm) {
  if (fm) ((float*)p)[idx] = v;
  else    ((u16*)p)[idx]   = f2bf(v);
}
__device__ __forceinline__ float load_any(const void* p, size_t i, u32 fm) {
  return fm ? ((const float*)p)[i] : bf2f(((const u16*)p)[i]);
}

enum { EPI_PLANES = 0, EPI_EMB = 1, EPI_SCORES = 2, EPI_OUT = 3 };

// ---- dtype detection: low u16 of fp32 data is random mantissa bits -> wild bf16 ----
__global__ void detect_kernel(const u32* __restrict__ x, u32* __restrict__ flag) {
  __shared__ int cnt;
  if (threadIdx.x == 0) cnt = 0;
  __syncthreads();
  int wild = 0;
  #pragma unroll
  for (int c = 0; c < 4; ++c) {
    u32 u = x[threadIdx.x * 4 + c];
    float a = fabsf(bf2f((u16)(u & 0xffff)));
    if (!(a <= 1e6f) || (a != 0.f && a < 1e-20f)) wild++;  // !(a<=..) catches NaN
  }
  atomicAdd(&cnt, wild);
  __syncthreads();
  if (threadIdx.x == 0) flag[0] = (cnt > 100) ? 1u : 0u;  // 1 = fp32 inputs
}

// ======================= fused one-shot prep =======================
// Block-range dispatch over a constexpr task table:
//   [0,9472)      : 8 weight transpose+3-plane decompositions (32x32 tiles)
//   [9472,9505)   : 8 bias converts -> f32
//   [9505,9761)   : centers -> 3 bf16 planes (vec4)
//   [9761,10017)  : c2[k] = sum_d centers[k][d]^2 (from raw centers)
struct PrepArgs {
  const void* wsrc[8];
  u16* wdst[8][3];
  const void* bsrc[8];
  float* bdst[8];
  const void* cen;
  u16* cd0; u16* cd1; u16* cd2;
  float* c2;
};

__global__ __launch_bounds__(256) void megaprep(PrepArgs P, const u32* __restrict__ flag) {
  __shared__ float t[32][33];
  const u32 fm = flag[0];
  const int b = blockIdx.x;
  const int tid = threadIdx.x;
  constexpr int RR[8] = {1024, 2048, 1024, 512, 256, 512, 1024, 2048};
  constexpr int CC[8] = {2048, 1024, 512, 256, 512, 1024, 2048, 1024};
  constexpr int WB[8] = {2048, 2048, 512, 128, 128, 512, 2048, 2048};
  constexpr int BN[8] = {2048, 1024, 512, 256, 512, 1024, 2048, 1024};
  constexpr int BB[8] = {8, 4, 2, 1, 2, 4, 8, 4};

  int s = 0;
  // ---- weight transpose+decomp tasks ----
  #pragma unroll
  for (int w = 0; w < 8; ++w) {
    if (b < s + WB[w]) {
      const int lb = b - s;
      const int Cw = CC[w], Rw = RR[w];
      const int tbx = lb % (Cw / 32), tby = lb / (Cw / 32);
      const int xx = tid & 31, yq = tid >> 5;
      #pragma unroll
      for (int yy = yq; yy < 32; yy += 8) {
        size_t src = (size_t)(tby * 32 + yy) * Cw + tbx * 32 + xx;
        t[yy][xx] = load_any(P.wsrc[w], src, fm);
      }
      __syncthreads();
      #pragma unroll
      for (int yy = yq; yy < 32; yy += 8) {
        float v = t[xx][yy];
        u16 h = f2bf(v);
        float r1 = v - bf2f(h);
        u16 m = f2bf(r1);
        u16 l = f2bf(r1 - bf2f(m));
        size_t dst = (size_t)(tbx * 32 + yy) * Rw + tby * 32 + xx;
        P.wdst[w][0][dst] = h; P.wdst[w][1][dst] = m; P.wdst[w][2][dst] = l;
      }
      return;
    }
    s += WB[w];
  }
  // ---- bias converts ----
  #pragma unroll
  for (int w = 0; w < 8; ++w) {
    if (b < s + BB[w]) {
      int i = (b - s) * 256 + tid;
      if (i < BN[w]) P.bdst[w][i] = load_any(P.bsrc[w], i, fm);
      return;
    }
    s += BB[w];
  }
  // ---- centers decomp (vec4): 1024*256 elems / (256 thr * 4) = 256 blocks ----
  if (b < s + 256) {
    int i = (b - s) * 256 + tid;      // vec4 index
    float v[4];
    if (fm) {
      float4 q = ((const float4*)P.cen)[i];
      v[0] = q.x; v[1] = q.y; v[2] = q.z; v[3] = q.w;
    } else {
      ushort4 q = ((const ushort4*)P.cen)[i];
      v[0] = bf2f(q.x); v[1] = bf2f(q.y); v[2] = bf2f(q.z); v[3] = bf2f(q.w);
    }
    ushort4 hh, mm, ll;
    u16* hp = (u16*)&hh; u16* mp = (u16*)&mm; u16* lp = (u16*)&ll;
    #pragma unroll
    for (int q = 0; q < 4; ++q) {
      u16 h = f2bf(v[q]);
      float r1 = v[q] - bf2f(h);
      u16 m = f2bf(r1);
      hp[q] = h; mp[q] = m; lp[q] = f2bf(r1 - bf2f(m));
    }
    ((ushort4*)P.cd0)[i] = hh; ((ushort4*)P.cd1)[i] = mm; ((ushort4*)P.cd2)[i] = ll;
    return;
  }
  s += 256;
  // ---- c2 from raw centers: 4 rows/block over 256 blocks ----
  {
    int w = (b - s) * 4 + (tid >> 6);
    int lane = tid & 63;
    float4 v;
    if (fm) v = *(const float4*)((const float*)P.cen + (size_t)w * 256 + lane * 4);
    else {
      ushort4 q = *(const ushort4*)((const u16*)P.cen + (size_t)w * 256 + lane * 4);
      v = make_float4(bf2f(q.x), bf2f(q.y), bf2f(q.z), bf2f(q.w));
    }
    float sq = v.x * v.x + v.y * v.y + v.z * v.z + v.w * v.w;
    #pragma unroll
    for (int off = 32; off; off >>= 1) sq += __shfl_down(sq, off);
    if (lane == 0) P.c2[w] = sq;
  }
}

// ---- x chunk -> 3 bf16 planes, vec4 (element offset; dtype handled device-side) ----
__global__ void decomp_x4(const void* __restrict__ in, u16* __restrict__ hi,
                          u16* __restrict__ mid, u16* __restrict__ lo,
                          int n4, size_t eoff4, const u32* __restrict__ flag) {
  int i = blockIdx.x * 256 + threadIdx.x;
  if (i >= n4) return;
  u32 fm = flag[0];
  float v[4];
  if (fm) {
    float4 q = ((const float4*)in)[eoff4 + i];
    v[0] = q.x; v[1] = q.y; v[2] = q.z; v[3] = q.w;
  } else {
    ushort4 q = ((const ushort4*)in)[eoff4 + i];
    v[0] = bf2f(q.x); v[1] = bf2f(q.y); v[2] = bf2f(q.z); v[3] = bf2f(q.w);
  }
  ushort4 hh, mm, ll;
  u16* hp = (u16*)&hh; u16* mp = (u16*)&mm; u16* lp = (u16*)&ll;
  #pragma unroll
  for (int q = 0; q < 4; ++q) {
    u16 h = f2bf(v[q]);
    float r1 = v[q] - bf2f(h);
    u16 m = f2bf(r1);
    hp[q] = h; mp[q] = m; lp[q] = f2bf(r1 - bf2f(m));
  }
  ((ushort4*)hi)[i] = hh; ((ushort4*)mid)[i] = mm; ((ushort4*)lo)[i] = ll;
}

// ---- async stage of one 128x32 bf16 tile (8KB) into LDS via global_load_lds ----
__device__ __forceinline__ void stage_tile128(const u16* __restrict__ g, u16* lbase,
                                              int Kst, int tid) {
  const int lane = tid & 63;
  const int wv   = tid >> 6;
  #pragma unroll
  for (int c = 0; c < 2; ++c) {
    const int li   = wv * 128 + c * 64 + lane;   // 16B-chunk index, 0..511
    const int row  = li >> 2;
    const int colb = (li & 3) * 16;
    const char* src = (const char*)g + (size_t)row * ((size_t)Kst * 2) + colb;
    u16* dst = lbase + (size_t)(wv * 128 + c * 64) * 8;  // wave-uniform
    __builtin_amdgcn_global_load_lds(
        (const __attribute__((address_space(1))) void*)src,
        (__attribute__((address_space(3))) void*)dst, 16, 0, 0);
  }
}

// Fully static GEMM body: C = act(sum_{pa+pw<=PCAP} Aplane[pa] @ Wplane[pw]^T + bias).
// 128x128 tile, BK=32, 4 waves, 4x4 MFMA 16x16x32 per wave (m92/m97 layout).
// XCD-chunked bijective block swizzle (identity when nwg%8!=0, m204).
// EPI_SCORES: fused per-block argmin -> per-row (min,idx) partials in outf[M][N/128].
template<int nA, int nW, int PCAP, int RELU, int EPI, int NOUT>
__device__ __forceinline__ void gemm_body(
    const u16* __restrict__ A0, const u16* __restrict__ A1, const u16* __restrict__ A2,
    const u16* __restrict__ W0, const u16* __restrict__ W1, const u16* __restrict__ W2,
    const float* __restrict__ bias, const float* __restrict__ c2p,
    u16* __restrict__ O0, u16* __restrict__ O1, u16* __restrict__ O2,
    float* __restrict__ outf, void* __restrict__ dout, size_t doff,
    u32 fm, int M, int N, int K, u16* lds)
{
  const int tid  = threadIdx.x;
  const int lane = tid & 63;
  const int wid  = tid >> 6;

  const int gx = gridDim.x, gy = gridDim.y;
  const int nwg = gx * gy;
  int bx = blockIdx.x, by = blockIdx.y;
  if ((nwg & 7) == 0) {
    int f0 = by * gx + bx;
    int sw = (f0 & 7) * (nwg >> 3) + (f0 >> 3);
    bx = sw % gx; by = sw / gx;
  }
  const int m0 = by * 128;
  const int n0 = bx * 128;
  const int wm = (wid & 1) * 64;
  const int wn = (wid >> 1) * 64;
  const u16* Ap[3] = {A0, A1, A2};
  const u16* Wp[3] = {W0, W1, W2};

  f32x4 acc[4][4];
  #pragma unroll
  for (int i = 0; i < 4; ++i)
    #pragma unroll
    for (int j = 0; j < 4; ++j)
      acc[i][j] = f32x4{0.f, 0.f, 0.f, 0.f};

  for (int k0 = 0; k0 < K; k0 += 32) {
    __syncthreads();
    #pragma unroll
    for (int p = 0; p < nA; ++p)
      stage_tile128(Ap[p] + (size_t)m0 * K + k0, lds + p * 4096, K, tid);
    #pragma unroll
    for (int q = 0; q < nW; ++q)
      stage_tile128(Wp[q] + (size_t)n0 * K + k0, lds + (nA + q) * 4096, K, tid);
    __syncthreads();

    short8 bfrag[nW][4];
    #pragma unroll
    for (int q = 0; q < nW; ++q)
      #pragma unroll
      for (int j = 0; j < 4; ++j) {
        int r = wn + j * 16 + (lane & 15);
        bfrag[q][j] = *(const short8*)&lds[(nA + q) * 4096 + r * 32 + (lane >> 4) * 8];
      }
    #pragma unroll
    for (int pa = 0; pa < nA; ++pa) {
      short8 afrag[4];
      #pragma unroll
      for (int i = 0; i < 4; ++i) {
        int r = wm + i * 16 + (lane & 15);
        afrag[i] = *(const short8*)&lds[pa * 4096 + r * 32 + (lane >> 4) * 8];
      }
      #pragma unroll
      for (int pw = 0; pw < nW; ++pw) {
        if (pa + pw <= PCAP) {
          #pragma unroll
          for (int i = 0; i < 4; ++i)
            #pragma unroll
            for (int j = 0; j < 4; ++j)
              acc[i][j] = __builtin_amdgcn_mfma_f32_16x16x32_bf16(
                  afrag[i], bfrag[pw][j], acc[i][j], 0, 0, 0);
        }
      }
    }
  }

  if constexpr (EPI == EPI_SCORES) {
    // fused argmin over this block's 128 cols (np first-index tie-break)
    __shared__ float2 sarr[2][128];
    #pragma unroll
    for (int i = 0; i < 4; ++i) {
      #pragma unroll
      for (int r = 0; r < 4; ++r) {
        float mv = 3.4e38f;
        int   mi = 1 << 30;
        #pragma unroll
        for (int j = 0; j < 4; ++j) {
          int col = n0 + wn + j * 16 + (lane & 15);
          float sv = c2p[col] - 2.f * acc[i][j][r];
          if (sv < mv) { mv = sv; mi = col; }   // j ascending => first-index kept
        }
        #pragma unroll
        for (int off = 1; off < 16; off <<= 1) {
          float ov = __shfl_xor(mv, off);
          int   oi = __shfl_xor(mi, off);
          if (ov < mv || (ov == mv && oi < mi)) { mv = ov; mi = oi; }
        }
        int lrow = wm + i * 16 + (lane >> 4) * 4 + r;
        if ((lane & 15) == 0) sarr[wn >> 6][lrow] = make_float2(mv, (float)mi);
      }
    }
    __syncthreads();
    if (tid < 128) {
      float2 a = sarr[0][tid], bb = sarr[1][tid];
      float v = a.x, ix = a.y;
      if (bb.x < v || (bb.x == v && bb.y < ix)) { v = bb.x; ix = bb.y; }
      ((float2*)outf)[(size_t)(m0 + tid) * (N >> 7) + (n0 >> 7)] = make_float2(v, ix);
    }
  } else {
    // epilogue: C/D layout col=lane&15, row=(lane>>4)*4+reg
    #pragma unroll
    for (int i = 0; i < 4; ++i) {
      int rbase = m0 + wm + i * 16 + ((lane >> 4) * 4);
      #pragma unroll
      for (int j = 0; j < 4; ++j) {
        int col = n0 + wn + j * 16 + (lane & 15);
        float bv = bias[col];
        #pragma unroll
        for (int r = 0; r < 4; ++r) {
          float v = acc[i][j][r] + bv;
          if (RELU) v = fmaxf(v, 0.f);
          size_t idx = (size_t)(rbase + r) * N + col;
          if (NOUT >= 1) {
            u16 h = f2bf(v);
            O0[idx] = h;
            if (NOUT >= 2) {
              float r1 = v - bf2f(h);
              u16 m = f2bf(r1);
              O1[idx] = m;
              if (NOUT >= 3) O2[idx] = f2bf(r1 - bf2f(m));
            }
          }
          if (EPI == EPI_EMB || EPI == EPI_OUT) mode_store(dout, doff + idx, v, fm);
        }
      }
    }
  }
}

template<int NA, int NW, int PCAP, int RELU, int EPI, int NOUT, int ARAW>
__global__ __launch_bounds__(256)
void gemm_kernel(const u16* A0, const u16* A1, const u16* A2,
                 const u16* W0, const u16* W1, const u16* W2,
                 const float* __restrict__ bias, const float* __restrict__ c2p,
                 u16* O0, u16* O1, u16* O2,
                 float* outf, void* dout, size_t doff,
                 const u32* __restrict__ flag, int M, int N, int K)
{
  __shared__ __align__(16) u16 lds[(NA + NW) * 4096];
  const u32 fm = flag[0];
  if (fm)
    gemm_body<NA, NW, PCAP, RELU, EPI, NOUT>(A0, A1, A2, W0, W1, W2, bias, c2p,
                                             O0, O1, O2, outf, dout, doff, fm, M, N, K, lds);
  else
    gemm_body<(ARAW ? 1 : NA), 1, PCAP, RELU, EPI, NOUT>(A0, A1, A2, W0, W1, W2, bias, c2p,
                                             O0, O1, O2, outf, dout, doff, fm, M, N, K, lds);
}

// final argmin over 8 per-block partials per row -> one-hot at d_out element offset
__global__ void argmin_final(const float2* __restrict__ pf, void* __restrict__ dout,
                             size_t doff, const u32* __restrict__ flag) {
  u32 fm  = flag[0];
  int row  = blockIdx.x * 4 + (threadIdx.x >> 6);
  int lane = threadIdx.x & 63;
  float v = 3.4e38f;
  int  mi = 1 << 30;
  if (lane < 8) {
    float2 e = pf[(size_t)row * 8 + lane];
    v = e.x; mi = (int)e.y;
  }
  #pragma unroll
  for (int off = 1; off < 8; off <<= 1) {
    float ov = __shfl_xor(v, off);
    int   oi = __shfl_xor(mi, off);
    if (ov < v || (ov == v && oi < mi)) { v = ov; mi = oi; }
  }
  int besti = __shfl(mi, 0);
  size_t eb = doff + (size_t)row * 1024 + lane * 16;
  if (fm) {
    float* op = (float*)dout;
    #pragma unroll
    for (int q = 0; q < 16; ++q)
      op[eb + q] = (lane * 16 + q == besti) ? 1.0f : 0.0f;
  } else {
    u16* op = (u16*)dout + eb;
    uint32_t w[8];
    #pragma unroll
    for (int q = 0; q < 8; ++q) {
      int c0 = lane * 16 + q * 2;
      w[q] = ((c0 == besti) ? 0x3F80u : 0u) | (((c0 + 1 == besti) ? 0x3F80u : 0u) << 16);
    }
    *(uint4*)op       = make_uint4(w[0], w[1], w[2], w[3]);
    *(uint4*)(op + 8) = make_uint4(w[4], w[5], w[6], w[7]);
  }
}

extern "C" void kernel_launch(void* const* d_in, const int* in_sizes, int n_in,
                              void* d_out, int out_size, void* d_ws, size_t ws_size,
                              hipStream_t stream) {
  const int Bn = 8192;
  const int ENC[5] = {1024, 2048, 1024, 512, 256};
  const int DEC[5] = {256, 512, 1024, 2048, 1024};

  const void* x = d_in[0];
  const void *We[4], *be[4], *Wd[4], *bd[4];
  for (int i = 0; i < 4; ++i) { We[i] = d_in[1 + 2 * i]; be[i] = d_in[2 + 2 * i]; }
  for (int i = 0; i < 4; ++i) { Wd[i] = d_in[9 + 2 * i]; bd[i] = d_in[10 + 2 * i]; }
  const void* centers = d_in[17];

  // ---- fixed workspace carve ----
  char* wsb = (char*)d_ws;
  size_t o = 0;
  auto carve = [&](size_t bytes) { void* p = wsb + o; o += (bytes + 63) & ~size_t(63); return p; };
  u32* flag = (u32*)carve(64);
  u16 *WTe[4][3], *WTd[4][3];
  for (int i = 0; i < 4; ++i)
    for (int p = 0; p < 3; ++p) WTe[i][p] = (u16*)carve((size_t)ENC[i] * ENC[i + 1] * 2);
  for (int i = 0; i < 4; ++i)
    for (int p = 0; p < 3; ++p) WTd[i][p] = (u16*)carve((size_t)DEC[i] * DEC[i + 1] * 2);
  float* bef[4]; float* bdf[4];
  for (int i = 0; i < 4; ++i) bef[i] = (float*)carve((size_t)ENC[i + 1] * 4);
  for (int i = 0; i < 4; ++i) bdf[i] = (float*)carve((size_t)DEC[i + 1] * 4);
  u16* cen[3];
  for (int p = 0; p < 3; ++p) cen[p] = (u16*)carve(1024 * 256 * 2);
  float* c2 = (float*)carve(1024 * 4);

  // ---- chunk size from remaining ws; per-chunk activation planes: 29184 B/row ----
  size_t rem = (ws_size > o) ? ws_size - o - 4096 : 0;
  int CH = 256;
  for (int c = 8192; c >= 256; c >>= 1)
    if ((size_t)c * 29184 <= rem) { CH = c; break; }
  const int nch = Bn / CH;

  u16* xp[3];  for (int p = 0; p < 3; ++p) xp[p]  = (u16*)carve((size_t)CH * 1024 * 2);
  u16* h1p[3]; for (int p = 0; p < 3; ++p) h1p[p] = (u16*)carve((size_t)CH * 2048 * 2);
  u16* h2p[3]; for (int p = 0; p < 3; ++p) h2p[p] = (u16*)carve((size_t)CH * 1024 * 2);
  u16* h3p[3]; for (int p = 0; p < 3; ++p) h3p[p] = (u16*)carve((size_t)CH * 512 * 2);
  u16* ep[3];  for (int p = 0; p < 3; ++p) ep[p]  = (u16*)carve((size_t)CH * 256 * 2);
  // overlays (stream-ordered reuse of dead regions):
  float2* pf = (float2*)xp[0];              // CH*64 B <= xp region CH*6144; xp dead after L0
  char* dreg = (char*)h1p[0];               // h1p+h2p region: CH*18432 B, dead after L1/L2
  u16* g1p[2] = {(u16*)dreg,                        (u16*)(dreg + (size_t)CH * 1024)};
  u16* g2p[2] = {(u16*)(dreg + (size_t)CH * 2048),  (u16*)(dreg + (size_t)CH * 4096)};
  u16* g3p[2] = {(u16*)(dreg + (size_t)CH * 6144),  (u16*)(dreg + (size_t)CH * 10240)};

  const size_t off_emb    = (size_t)Bn * 1024;
  const size_t off_labels = (size_t)Bn * 1280;

  // ---- prep: detect dtype, then one fused prep kernel ----
  detect_kernel<<<1, 256, 0, stream>>>((const u32*)x, flag);
  {
    PrepArgs P;
    for (int i = 0; i < 4; ++i) {
      P.wsrc[i] = We[i];     P.bsrc[i] = be[i];     P.bdst[i] = bef[i];
      P.wsrc[4 + i] = Wd[i]; P.bsrc[4 + i] = bd[i]; P.bdst[4 + i] = bdf[i];
      for (int p = 0; p < 3; ++p) { P.wdst[i][p] = WTe[i][p]; P.wdst[4 + i][p] = WTd[i][p]; }
    }
    P.cen = centers; P.cd0 = cen[0]; P.cd1 = cen[1]; P.cd2 = cen[2]; P.c2 = c2;
    megaprep<<<10017, 256, 0, stream>>>(P, flag);
  }

  const int GY = CH / 128;
  for (int c = 0; c < nch; ++c) {
    decomp_x4<<<(CH * 1024 / 4 + 255) / 256, 256, 0, stream>>>(
        x, xp[0], xp[1], xp[2], CH * 1024 / 4, (size_t)c * CH * 256, flag);

    // encoder
    gemm_kernel<3, 3, 2, 1, EPI_PLANES, 3, 1><<<dim3(16, GY), 256, 0, stream>>>(
        xp[0], xp[1], xp[2], WTe[0][0], WTe[0][1], WTe[0][2], bef[0], nullptr,
        h1p[0], h1p[1], h1p[2], nullptr, nullptr, 0, flag, CH, 2048, 1024);
    gemm_kernel<3, 3, 2, 1, EPI_PLANES, 3, 0><<<dim3(8, GY), 256, 0, stream>>>(
        h1p[0], h1p[1], h1p[2], WTe[1][0], WTe[1][1], WTe[1][2], bef[1], nullptr,
        h2p[0], h2p[1], h2p[2], nullptr, nullptr, 0, flag, CH, 1024, 2048);
    gemm_kernel<3, 3, 2, 1, EPI_PLANES, 3, 0><<<dim3(4, GY), 256, 0, stream>>>(
        h2p[0], h2p[1], h2p[2], WTe[2][0], WTe[2][1], WTe[2][2], bef[2], nullptr,
        h3p[0], h3p[1], h3p[2], nullptr, nullptr, 0, flag, CH, 512, 1024);
    gemm_kernel<3, 3, 2, 0, EPI_EMB, 3, 0><<<dim3(2, GY), 256, 0, stream>>>(
        h3p[0], h3p[1], h3p[2], WTe[3][0], WTe[3][1], WTe[3][2], bef[3], nullptr,
        ep[0], ep[1], ep[2], nullptr, d_out, off_emb + (size_t)c * CH * 256,
        flag, CH, 256, 512);

    // scores (fused per-block argmin) + final argmin/one-hot
    gemm_kernel<3, 3, 2, 0, EPI_SCORES, 0, 0><<<dim3(8, GY), 256, 0, stream>>>(
        ep[0], ep[1], ep[2], cen[0], cen[1], cen[2], nullptr, c2,
        nullptr, nullptr, nullptr, (float*)pf, nullptr, 0, flag, CH, 1024, 256);
    argmin_final<<<CH / 4, 256, 0, stream>>>(pf, d_out,
        off_labels + (size_t)c * CH * 1024, flag);

    // decoder
    gemm_kernel<2, 2, 1, 1, EPI_PLANES, 2, 0><<<dim3(4, GY), 256, 0, stream>>>(
        ep[0], ep[1], nullptr, WTd[0][0], WTd[0][1], nullptr, bdf[0], nullptr,
        g1p[0], g1p[1], nullptr, nullptr, nullptr, 0, flag, CH, 512, 256);
    gemm_kernel<2, 2, 1, 1, EPI_PLANES, 2, 0><<<dim3(8, GY), 256, 0, stream>>>(
        g1p[0], g1p[1], nullptr, WTd[1][0], WTd[1][1], nullptr, bdf[1], nullptr,
        g2p[0], g2p[1], nullptr, nullptr, nullptr, 0, flag, CH, 1024, 512);
    gemm_kernel<2, 2, 1, 1, EPI_PLANES, 2, 0><<<dim3(16, GY), 256, 0, stream>>>(
        g2p[0], g2p[1], nullptr, WTd[2][0], WTd[2][1], nullptr, bdf[2], nullptr,
        g3p[0], g3p[1], nullptr, nullptr, nullptr, 0, flag, CH, 2048, 1024);
    gemm_kernel<2, 2, 1, 0, EPI_OUT, 0, 0><<<dim3(8, GY), 256, 0, stream>>>(
        g3p[0], g3p[1], nullptr, WTd[3][0], WTd[3][1], nullptr, bdf[3], nullptr,
        nullptr, nullptr, nullptr, nullptr, d_out, (size_t)c * CH * 1024,
        flag, CH, 1024, 2048);
  }

  (void)in_sizes; (void)n_in; (void)out_size;
}